// Round 7
// baseline (122.174 us; speedup 1.0000x reference)
//
#include <hip/hip_runtime.h>

typedef __attribute__((ext_vector_type(8))) short short8;   // 8 bf16 = 4 VGPR (MFMA A/B frag)
typedef __attribute__((ext_vector_type(4))) float f32x4;    // MFMA C/D frag
typedef __attribute__((ext_vector_type(2))) float f32x2;

#define SDIM 32
#define HDIM 34
#define NEXP 12
#define ACOL 256
#define SPB  256
#define MAXROWS 448        // max padded rows = 256 + 12*15 = 436, round up
#define STGS 132           // per-wave staging stride (floats): 128+4 -> 2-way banks (free)

// fp32 -> bf16 (round-to-nearest-ish), pack two into one dword
__device__ __forceinline__ unsigned int bpack(float lo, float hi) {
    unsigned int a = __builtin_bit_cast(unsigned int, lo);
    unsigned int b = __builtin_bit_cast(unsigned int, hi);
    return ((a + 0x8000u) >> 16) | ((b + 0x8000u) & 0xffff0000u);
}

__global__ __launch_bounds__(256, 2) void actor_kernel(
    const float* __restrict__ states,
    const int*   __restrict__ epoch_idx,
    const float* __restrict__ W1,
    const float* __restrict__ b1,
    const float* __restrict__ Wout,
    const float* __restrict__ bout,
    const int*   __restrict__ mask,
    float*       __restrict__ out,
    int nB)
{
    // xs: 64 B/row = bf16 k0..31 in 4 16B chunks, chunk c at (c ^ ((row>>2)&3)).
    __shared__ __align__(16) unsigned int xs[MAXROWS * 16];  // 28672 B
    __shared__ unsigned int   xt[MAXROWS];                   // 1792 B (bf16 pair k32,33)
    __shared__ unsigned short rowid[MAXROWS];                // 896 B
    __shared__ __align__(16) float stg[4][16 * STGS];        // 33792 B private per-wave slots
    __shared__ int cnt[NEXP], goff[NEXP], ntl[NEXP];
    // total ~65.4 KB -> 2 blocks/CU

    float* w1s = &stg[0][0];             // aliased: used only in phases 0-1
    float* b1s = w1s + HDIM * SDIM;

    const int t  = threadIdx.x;
    const int s0 = blockIdx.x * SPB;

    // ---- phase 0: stage W1/b1, zero counters, sentinel rowid ----
    for (int i = t; i < HDIM * SDIM; i += 256) w1s[i] = W1[i];
    if (t < HDIM) b1s[t] = b1[t];
    if (t < NEXP) cnt[t] = 0;
    for (int i = t; i < MAXROWS; i += 256) rowid[i] = 0xFFFFu;

    const int  sidx  = s0 + t;
    const bool valid = (sidx < nB);
    float sr[SDIM];
    int e = 0;
    if (valid) {
        const f32x4* sp = (const f32x4*)(states + (size_t)sidx * SDIM);
        #pragma unroll
        for (int q = 0; q < SDIM / 4; ++q) {
            f32x4 v = sp[q];
            sr[4*q+0] = v[0]; sr[4*q+1] = v[1]; sr[4*q+2] = v[2]; sr[4*q+3] = v[3];
        }
        e = epoch_idx[sidx];
    }
    __syncthreads();                 // cnt zeroed, w1s staged

    int rank = 0;
    if (valid) rank = atomicAdd(&cnt[e], 1);
    __syncthreads();                 // cnt final

    // ---- t0: exclusive scan into 16-padded bases; everyone: trunk GEMV ----
    if (t == 0) {
        int base = 0;
        #pragma unroll
        for (int i = 0; i < NEXP; ++i) {
            goff[i] = base;
            int nt = (cnt[i] + 15) >> 4;
            ntl[i] = nt;
            base += nt << 4;
        }
    }
    float x[HDIM];
    if (valid) {
        #pragma unroll 2
        for (int h = 0; h < HDIM; ++h) {
            float acc = b1s[h];
            const float4* wr = (const float4*)(w1s + h * SDIM);
            #pragma unroll
            for (int q = 0; q < SDIM / 4; ++q) {
                float4 wv = wr[q];
                acc = fmaf(sr[4*q+0], wv.x, acc);
                acc = fmaf(sr[4*q+1], wv.y, acc);
                acc = fmaf(sr[4*q+2], wv.z, acc);
                acc = fmaf(sr[4*q+3], wv.w, acc);
            }
            x[h] = fmaxf(acc, 0.0f);
        }
    }
    __syncthreads();                 // goff ready; w1s reads done

    // ---- phase 2: write bf16 x row into sorted+padded slot (swizzled) ----
    if (valid) {
        const int slot = goff[e] + rank;
        const unsigned sw = (((unsigned)slot >> 2) & 3u) << 4;
        char* rbase = (char*)xs + slot * 64;
        unsigned d[16];
        #pragma unroll
        for (int k = 0; k < 16; ++k) d[k] = bpack(x[2*k], x[2*k+1]);
        #pragma unroll
        for (int c = 0; c < 4; ++c) {
            f32x4 q;
            q[0] = __builtin_bit_cast(float, d[4*c+0]);
            q[1] = __builtin_bit_cast(float, d[4*c+1]);
            q[2] = __builtin_bit_cast(float, d[4*c+2]);
            q[3] = __builtin_bit_cast(float, d[4*c+3]);
            *(f32x4*)(rbase + (((unsigned)(c * 16)) ^ sw)) = q;
        }
        xt[slot]    = bpack(x[32], x[33]);
        rowid[slot] = (unsigned short)t;
    }
    __syncthreads();                 // xs/xt/rowid visible — LAST barrier in kernel

    // ---- phase 3: barrier-free. Wave-pair p owns tiles of parity p; ----
    // ---- within pair, wave qh owns a 128-action column half.        ----
    const int wv   = t >> 6;
    const int lane = t & 63;
    const int p    = wv >> 1;        // tile parity this wave serves
    const int qh   = wv & 1;         // column half (0: actions 0-127, 1: 128-255)
    const int r    = lane & 15;
    const int g    = lane >> 4;
    const int hb   = qh * 128;       // global action base of this wave's half
    float* mystg   = stg[wv];        // private 16x132 staging slot
    const float NEG = -1e9f;
    const int m0 = mask[hb + 2 * lane];
    const int m1 = mask[hb + 2 * lane + 1];

    float* outb = out + (size_t)s0 * ACOL;

    for (int e2 = 0; e2 < NEXP; ++e2) {
        const int ntiles = ntl[e2];
        if (ntiles == 0) continue;

        // W fragments: 8 col-tiles covering this wave's 128 actions
        short8   bf1[8];
        unsigned w2[8];
        float    bias[8];
        #pragma unroll
        for (int j = 0; j < 8; ++j) {
            const int col = hb + j * 16 + r;
            const float* wr = Wout + ((size_t)e2 * ACOL + col) * HDIM;
            const float2* wp = (const float2*)(wr + g * 8);
            float2 p0 = wp[0], p1 = wp[1], p2 = wp[2], p3 = wp[3];
            uint4 q1 = make_uint4(bpack(p0.x, p0.y), bpack(p1.x, p1.y),
                                  bpack(p2.x, p2.y), bpack(p3.x, p3.y));
            bf1[j] = __builtin_bit_cast(short8, q1);
            w2[j]  = (g == 0) ? bpack(wr[32], wr[33]) : 0u;
            bias[j] = bout[e2 * ACOL + col];
        }

        const int tb  = goff[e2];
        const int gt0 = tb >> 4;                 // global tile index of first tile
        for (int st = 0; st < ntiles; ++st) {
            if (((gt0 + st) & 1) != p) continue; // parity split across wave pairs
            const int rb  = tb + (st << 4);
            const int row = rb + r;
            const unsigned sw = (((unsigned)row >> 2) & 3u) << 4;
            const char* rp = (const char*)xs + row * 64;
            short8 a1 = *(const short8*)(rp + (((unsigned)(g * 16)) ^ sw));
            short8 a2 = __builtin_bit_cast(short8,
                          make_uint4(g == 0 ? xt[row] : 0u, 0u, 0u, 0u));

            // compute 16 states x 128 actions (this wave's half-tile)
            #pragma unroll
            for (int j = 0; j < 8; ++j) {
                f32x4 a = {bias[j], bias[j], bias[j], bias[j]};
                a = __builtin_amdgcn_mfma_f32_16x16x32_bf16(a1, bf1[j], a, 0, 0, 0);
                short8 b2 = __builtin_bit_cast(short8,
                              make_uint4(w2[j], 0u, 0u, 0u));
                a = __builtin_amdgcn_mfma_f32_16x16x32_bf16(a2, b2, a, 0, 0, 0);
                // stage: acc[i] = D[state 4g+i][action hb+16j+r]
                #pragma unroll
                for (int i = 0; i < 4; ++i)
                    mystg[(4 * g + i) * STGS + 16 * j + r] = a[i];
            }
            // intra-wave read-back + 512B contiguous stores (lgkmcnt-ordered)
            #pragma unroll
            for (int lrow = 0; lrow < 16; ++lrow) {
                const unsigned rid = rowid[rb + lrow];
                f32x2 v = *(const f32x2*)&mystg[lrow * STGS + 2 * lane];
                v[0] = m0 ? v[0] : NEG;
                v[1] = m1 ? v[1] : NEG;
                if (rid != 0xFFFFu)
                    __builtin_nontemporal_store(v,
                        (f32x2*)(outb + (size_t)rid * ACOL + hb + 2 * lane));
            }
        }
    }
}

extern "C" void kernel_launch(void* const* d_in, const int* in_sizes, int n_in,
                              void* d_out, int out_size, void* d_ws, size_t ws_size,
                              hipStream_t stream) {
    const float* states    = (const float*)d_in[0];
    const int*   epoch_idx = (const int*)  d_in[1];
    const float* W1        = (const float*)d_in[2];
    const float* b1        = (const float*)d_in[3];
    const float* Wout      = (const float*)d_in[4];
    const float* bout      = (const float*)d_in[5];
    const int*   mask      = (const int*)  d_in[6];
    float*       out       = (float*)d_out;

    const int nB   = in_sizes[0] / SDIM;
    const int grid = (nB + SPB - 1) / SPB;
    actor_kernel<<<grid, 256, 0, stream>>>(states, epoch_idx, W1, b1,
                                           Wout, bout, mask, out, nB);
}

// Round 8
// 116.707 us; speedup vs baseline: 1.0468x; 1.0468x over previous
//
#include <hip/hip_runtime.h>

typedef __attribute__((ext_vector_type(8))) short short8;   // 8 bf16 (MFMA A/B frag)
typedef __attribute__((ext_vector_type(4))) float f32x4;

#define SDIM 32
#define HDIM 34
#define NEXP 12
#define ACOL 256

// fp32 -> bf16 (round-to-nearest-ish), pack two into one dword
__device__ __forceinline__ unsigned int bpack(float lo, float hi) {
    unsigned int a = __builtin_bit_cast(unsigned int, lo);
    unsigned int b = __builtin_bit_cast(unsigned int, hi);
    return ((a + 0x8000u) >> 16) | ((b + 0x8000u) & 0xffff0000u);
}

// ---- K1: per-block expert histogram -> cnts[b*12+e] ----
__global__ __launch_bounds__(256) void k1_count(
    const int* __restrict__ epoch_idx, int* __restrict__ cnts, int nB)
{
    __shared__ int lc[NEXP];
    const int t = threadIdx.x;
    if (t < NEXP) lc[t] = 0;
    __syncthreads();
    const int sidx = blockIdx.x * 256 + t;
    if (sidx < nB) atomicAdd(&lc[epoch_idx[sidx]], 1);
    __syncthreads();
    if (t < NEXP) cnts[blockIdx.x * NEXP + t] = lc[t];
}

// ---- K2: reduce -> hist[12]; 256-row chunk scan -> cb[13]; zero cursors ----
__global__ __launch_bounds__(256) void k2_scan(
    const int* __restrict__ cnts, int* __restrict__ hist,
    int* __restrict__ cb, int* __restrict__ cur, int nblk)
{
    __shared__ int part[NEXP][17];
    const int t = threadIdx.x;
    const int e = t >> 4, p = t & 15;
    if (e < NEXP) {
        int s = 0;
        #pragma unroll 4
        for (int b = p; b < nblk; b += 16) s += cnts[b * NEXP + e];
        part[e][p] = s;
    }
    __syncthreads();
    if (t < NEXP) {
        int h = 0;
        #pragma unroll
        for (int q = 0; q < 16; ++q) h += part[t][q];
        hist[t] = h;
        cur[t]  = 0;
    }
    __syncthreads();
    if (t == 0) {
        int c = 0;
        #pragma unroll
        for (int i = 0; i < NEXP; ++i) { cb[i] = c; c += (hist[i] + 255) >> 8; }
        cb[NEXP] = c;
    }
}

// ---- K3: trunk GEMV + scatter bf16 x-rows into expert-sorted slots ----
__global__ __launch_bounds__(256) void k3_trunk(
    const float* __restrict__ states, const int* __restrict__ epoch_idx,
    const float* __restrict__ W1, const float* __restrict__ b1,
    const int* __restrict__ cb, int* __restrict__ cur,
    uint4* __restrict__ xg, unsigned int* __restrict__ xtg,
    int* __restrict__ idxg, int nB)
{
    __shared__ float w1s[HDIM * SDIM];
    __shared__ float b1s[HDIM];
    __shared__ int lc[NEXP], lbase[NEXP], lcb[NEXP];

    const int t = threadIdx.x;
    for (int i = t; i < HDIM * SDIM; i += 256) w1s[i] = W1[i];
    if (t < HDIM) b1s[t] = b1[t];
    if (t < NEXP) lc[t] = 0;

    const int  sidx  = blockIdx.x * 256 + t;
    const bool valid = (sidx < nB);
    float sr[SDIM];
    int e = 0;
    if (valid) {
        const f32x4* sp = (const f32x4*)(states + (size_t)sidx * SDIM);
        #pragma unroll
        for (int q = 0; q < SDIM / 4; ++q) {
            f32x4 v = sp[q];
            sr[4*q+0] = v[0]; sr[4*q+1] = v[1]; sr[4*q+2] = v[2]; sr[4*q+3] = v[3];
        }
        e = epoch_idx[sidx];
    }
    __syncthreads();                 // lc zeroed, w1s staged

    int rank = 0;
    if (valid) rank = atomicAdd(&lc[e], 1);
    __syncthreads();                 // lc final

    if (t < NEXP) {                  // reserve global range for this block
        lbase[t] = atomicAdd(&cur[t], lc[t]);
        lcb[t]   = cb[t];
    }
    float x[HDIM];
    if (valid) {
        #pragma unroll 2
        for (int h = 0; h < HDIM; ++h) {
            float acc = b1s[h];
            const float4* wr = (const float4*)(w1s + h * SDIM);
            #pragma unroll
            for (int q = 0; q < SDIM / 4; ++q) {
                float4 wv = wr[q];
                acc = fmaf(sr[4*q+0], wv.x, acc);
                acc = fmaf(sr[4*q+1], wv.y, acc);
                acc = fmaf(sr[4*q+2], wv.z, acc);
                acc = fmaf(sr[4*q+3], wv.w, acc);
            }
            x[h] = fmaxf(acc, 0.0f);
        }
    }
    __syncthreads();                 // lbase/lcb ready

    if (valid) {
        const int slot = (lcb[e] << 8) + lbase[e] + rank;
        unsigned d[17];
        #pragma unroll
        for (int k = 0; k < 17; ++k) d[k] = bpack(x[2*k], x[2*k+1]);
        uint4* xr = xg + (size_t)slot * 4;
        xr[0] = make_uint4(d[0],  d[1],  d[2],  d[3]);
        xr[1] = make_uint4(d[4],  d[5],  d[6],  d[7]);
        xr[2] = make_uint4(d[8],  d[9],  d[10], d[11]);
        xr[3] = make_uint4(d[12], d[13], d[14], d[15]);
        xtg[slot]  = d[16];          // k32,33
        idxg[slot] = sidx;           // original state index
    }
}

// ---- K4: dense single-expert GEMM; barrier-free; plain 256B stores ----
__global__ __launch_bounds__(256, 4) void k4_gemm(
    const float* __restrict__ Wout, const float* __restrict__ bout,
    const int* __restrict__ mask,
    const uint4* __restrict__ xg, const unsigned int* __restrict__ xtg,
    const int* __restrict__ idxg,
    const int* __restrict__ cb, const int* __restrict__ hist,
    float* __restrict__ out)
{
    __shared__ float stg[4][16 * 68];   // private per-wave transpose slab, ~17.4 KB

    const int bh   = blockIdx.x;
    const int b    = bh >> 1;           // chunk id
    const int half = bh & 1;            // tiles 0-7 / 8-15
    if (b >= cb[NEXP]) return;

    int e = 0;
    while (e < NEXP - 1 && b >= cb[e + 1]) ++e;
    int nvalid = hist[e] - ((b - cb[e]) << 8);
    if (nvalid > 256) nvalid = 256;
    const int ntt = (nvalid + 15) >> 4;
    const int st0 = half * 8;
    const int st1 = (st0 + 8 < ntt) ? st0 + 8 : ntt;
    if (st0 >= st1) return;

    const int t = threadIdx.x;
    const int wv = t >> 6, lane = t & 63;
    const int r = lane & 15, g = lane >> 4;
    const int m = mask[wv * 64 + lane];
    const float NEG = -1e9f;

    // this expert's W fragments: wave wv covers actions [wv*64, wv*64+64)
    short8   bf[4];
    unsigned w2[4];
    float    bias[4];
    #pragma unroll
    for (int j = 0; j < 4; ++j) {
        const int col = wv * 64 + j * 16 + r;
        const float* wr = Wout + ((size_t)e * ACOL + col) * HDIM;
        const float2* wp = (const float2*)(wr + g * 8);
        float2 p0 = wp[0], p1 = wp[1], p2 = wp[2], p3 = wp[3];
        uint4 q1 = make_uint4(bpack(p0.x, p0.y), bpack(p1.x, p1.y),
                              bpack(p2.x, p2.y), bpack(p3.x, p3.y));
        bf[j]  = __builtin_bit_cast(short8, q1);
        w2[j]  = (g == 0) ? bpack(wr[32], wr[33]) : 0u;
        bias[j] = bout[e * ACOL + col];
    }

    const uint4*        xb   = xg   + ((size_t)b << 10);   // chunk base: 256 rows * 4 uint4
    const unsigned int* xtb  = xtg  + (b << 8);
    const int*          idxb = idxg + (b << 8);
    float* mystg = stg[wv];

    for (int st = st0; st < st1; ++st) {
        const int rb  = st << 4;
        const int row = rb + r;
        short8 a1 = __builtin_bit_cast(short8, xb[row * 4 + g]);   // 1KB/instr coalesced
        const unsigned xtv = (g == 0) ? xtb[row] : 0u;
        short8 a2 = __builtin_bit_cast(short8, make_uint4(xtv, 0u, 0u, 0u));

        #pragma unroll
        for (int j = 0; j < 4; ++j) {
            f32x4 a = {bias[j], bias[j], bias[j], bias[j]};
            a = __builtin_amdgcn_mfma_f32_16x16x32_bf16(a1, bf[j], a, 0, 0, 0);
            short8 b2 = __builtin_bit_cast(short8, make_uint4(w2[j], 0u, 0u, 0u));
            a = __builtin_amdgcn_mfma_f32_16x16x32_bf16(a2, b2, a, 0, 0, 0);
            #pragma unroll
            for (int i = 0; i < 4; ++i)
                mystg[(4 * g + i) * 68 + 16 * j + r] = a[i];   // 2-way banks (free)
        }

        const int nrow = nvalid - rb;
        #pragma unroll
        for (int lrow = 0; lrow < 16; ++lrow) {
            if (lrow < nrow) {
                const int rid = idxb[rb + lrow];               // uniform -> scalar load
                float v = mystg[lrow * 68 + lane];
                v = m ? v : NEG;
                out[(size_t)rid * ACOL + wv * 64 + lane] = v;  // plain store, 256B/instr
            }
        }
    }
}

extern "C" void kernel_launch(void* const* d_in, const int* in_sizes, int n_in,
                              void* d_out, int out_size, void* d_ws, size_t ws_size,
                              hipStream_t stream) {
    const float* states    = (const float*)d_in[0];
    const int*   epoch_idx = (const int*)  d_in[1];
    const float* W1        = (const float*)d_in[2];
    const float* b1        = (const float*)d_in[3];
    const float* Wout      = (const float*)d_in[4];
    const float* bout      = (const float*)d_in[5];
    const int*   mask      = (const int*)  d_in[6];
    float*       out       = (float*)d_out;

    const int nB       = in_sizes[0] / SDIM;
    const int nblk     = (nB + 255) / 256;
    const int nchk_max = nblk + NEXP;

    char* ws = (char*)d_ws;
    int* hist = (int*)(ws + 0);     // 12 ints
    int* cb   = (int*)(ws + 64);    // 13 ints
    int* cur  = (int*)(ws + 128);   // 12 ints
    int* cnts = (int*)(ws + 256);   // nblk*12 ints
    size_t o_idx = 256 + (((size_t)nblk * NEXP * 4 + 255) & ~(size_t)255);
    size_t o_xt  = o_idx + (((size_t)nchk_max * 1024 + 255) & ~(size_t)255);
    size_t o_x   = o_xt  + (((size_t)nchk_max * 1024 + 255) & ~(size_t)255);
    int*          idxg = (int*)(ws + o_idx);
    unsigned int* xtg  = (unsigned int*)(ws + o_xt);
    uint4*        xg   = (uint4*)(ws + o_x);          // nchk_max*256 rows * 64B

    k1_count<<<nblk, 256, 0, stream>>>(epoch_idx, cnts, nB);
    k2_scan<<<1, 256, 0, stream>>>(cnts, hist, cb, cur, nblk);
    k3_trunk<<<nblk, 256, 0, stream>>>(states, epoch_idx, W1, b1,
                                       cb, cur, xg, xtg, idxg, nB);
    k4_gemm<<<nchk_max * 2, 256, 0, stream>>>(Wout, bout, mask,
                                              xg, xtg, idxg, cb, hist, out);
}

// Round 9
// 87.380 us; speedup vs baseline: 1.3982x; 1.3356x over previous
//
#include <hip/hip_runtime.h>

typedef __attribute__((ext_vector_type(8))) short short8;   // 8 bf16 (MFMA A/B frag)
typedef __attribute__((ext_vector_type(4))) float f32x4;
typedef __attribute__((ext_vector_type(4))) int   i32x4;

#define SDIM 32
#define HDIM 34
#define NEXP 12
#define ACOL 256
#define SPB  256
#define MAXROWS 448        // max padded rows = 256 + 12*15 = 436, round up
#define STG_STRIDE 260     // +4 pad: 2-way LDS banks only (free)

// raw barrier: waits LDS ops only, never drains global stores (T4)
#define BAR_LGKM() asm volatile("s_waitcnt lgkmcnt(0)\n\ts_barrier" ::: "memory")

// fp32 -> bf16 (round-to-nearest-ish), pack two into one dword
__device__ __forceinline__ unsigned int bpack(float lo, float hi) {
    unsigned int a = __builtin_bit_cast(unsigned int, lo);
    unsigned int b = __builtin_bit_cast(unsigned int, hi);
    return ((a + 0x8000u) >> 16) | ((b + 0x8000u) & 0xffff0000u);
}

// ---- k0: pack Wout into fragment-ordered bf16 records ----
// wpack[((e*4+wv)*4+j)*64 + lane] = 8 bf16 of W[col=wv*64+j*16+(lane&15)][k=8g..8g+7]
__global__ __launch_bounds__(256) void k0_wpack(
    const float* __restrict__ Wout, uint4* __restrict__ wpack,
    unsigned int* __restrict__ w2p)
{
    const int tid = blockIdx.x * 256 + threadIdx.x;
    if (tid >= NEXP * 4 * 4 * 64) return;
    const int lane = tid & 63;
    const int j    = (tid >> 6) & 3;
    const int wvv  = (tid >> 8) & 3;
    const int e    = tid >> 10;
    const int r = lane & 15, g = lane >> 4;
    const int col = wvv * 64 + j * 16 + r;
    const float* wr = Wout + ((size_t)e * ACOL + col) * HDIM;
    uint4 q;
    q.x = bpack(wr[g*8+0], wr[g*8+1]);
    q.y = bpack(wr[g*8+2], wr[g*8+3]);
    q.z = bpack(wr[g*8+4], wr[g*8+5]);
    q.w = bpack(wr[g*8+6], wr[g*8+7]);
    wpack[tid] = q;
    if (tid < NEXP * ACOL) {                       // w2: k=32,33 per (e,col)
        const float* wr2 = Wout + (size_t)tid * HDIM;
        w2p[tid] = bpack(wr2[32], wr2[33]);
    }
}

__global__ __launch_bounds__(256, 2) void actor_kernel(
    const float* __restrict__ states,
    const int*   __restrict__ epoch_idx,
    const float* __restrict__ W1,
    const float* __restrict__ b1,
    const uint4* __restrict__ wpack,
    const unsigned int* __restrict__ w2p,
    const float* __restrict__ bout,
    const int*   __restrict__ mask,
    float*       __restrict__ out,
    int nB)
{
    // xs: 64 B/row = bf16 k0..31 in 4 16B chunks, chunk c at (c ^ ((row>>2)&3)).
    __shared__ __align__(16) unsigned int xs[MAXROWS * 16];  // 28672 B
    __shared__ unsigned int   xt[MAXROWS];                   // 1792 B (bf16 k32,33)
    __shared__ unsigned short rowid[MAXROWS];                // 896 B
    __shared__ __align__(16) float stg[2][16 * STG_STRIDE];  // 33280 B double-buffer
    __shared__ int cnt[NEXP], goff[NEXP], ntl[NEXP];
    // total ~65.8 KB -> 2 blocks/CU

    float* w1s = &stg[0][0];             // aliased: phases 0-1 only
    float* b1s = w1s + HDIM * SDIM;

    const int t  = threadIdx.x;
    const int s0 = blockIdx.x * SPB;

    // ---- phase 0 ----
    for (int i = t; i < HDIM * SDIM; i += 256) w1s[i] = W1[i];
    if (t < HDIM) b1s[t] = b1[t];
    if (t < NEXP) cnt[t] = 0;
    for (int i = t; i < MAXROWS; i += 256) rowid[i] = 0xFFFFu;

    const int  sidx  = s0 + t;
    const bool valid = (sidx < nB);
    float sr[SDIM];
    int e = 0;
    if (valid) {
        const f32x4* sp = (const f32x4*)(states + (size_t)sidx * SDIM);
        #pragma unroll
        for (int q = 0; q < SDIM / 4; ++q) {
            f32x4 v = sp[q];
            sr[4*q+0] = v[0]; sr[4*q+1] = v[1]; sr[4*q+2] = v[2]; sr[4*q+3] = v[3];
        }
        e = epoch_idx[sidx];
    }
    __syncthreads();                 // cnt zeroed, w1s staged

    int rank = 0;
    if (valid) rank = atomicAdd(&cnt[e], 1);
    __syncthreads();                 // cnt final

    if (t == 0) {
        int base = 0;
        #pragma unroll
        for (int i = 0; i < NEXP; ++i) {
            goff[i] = base;
            int nt = (cnt[i] + 15) >> 4;
            ntl[i] = nt;
            base += nt << 4;
        }
    }
    float x[HDIM];
    if (valid) {
        #pragma unroll 2
        for (int h = 0; h < HDIM; ++h) {
            float acc = b1s[h];
            const float4* wr = (const float4*)(w1s + h * SDIM);
            #pragma unroll
            for (int q = 0; q < SDIM / 4; ++q) {
                float4 wv = wr[q];
                acc = fmaf(sr[4*q+0], wv.x, acc);
                acc = fmaf(sr[4*q+1], wv.y, acc);
                acc = fmaf(sr[4*q+2], wv.z, acc);
                acc = fmaf(sr[4*q+3], wv.w, acc);
            }
            x[h] = fmaxf(acc, 0.0f);
        }
    }
    __syncthreads();                 // goff ready; w1s reads done

    // ---- phase 2: scatter bf16 x row into sorted+padded slot (swizzled) ----
    if (valid) {
        const int slot = goff[e] + rank;
        const unsigned sw = (((unsigned)slot >> 2) & 3u) << 4;
        char* rbase = (char*)xs + slot * 64;
        unsigned d[16];
        #pragma unroll
        for (int k = 0; k < 16; ++k) d[k] = bpack(x[2*k], x[2*k+1]);
        #pragma unroll
        for (int c = 0; c < 4; ++c) {
            f32x4 q;
            q[0] = __builtin_bit_cast(float, d[4*c+0]);
            q[1] = __builtin_bit_cast(float, d[4*c+1]);
            q[2] = __builtin_bit_cast(float, d[4*c+2]);
            q[3] = __builtin_bit_cast(float, d[4*c+3]);
            *(f32x4*)(rbase + (((unsigned)(c * 16)) ^ sw)) = q;
        }
        xt[slot]    = bpack(x[32], x[33]);
        rowid[slot] = (unsigned short)t;
    }
    __syncthreads();                 // xs/xt/rowid visible

    // ---- phase 3: MFMA + dbuf staged transpose; 1 barrier/tile; plain stores ----
    const int wv   = t >> 6;
    const int lane = t & 63;
    const int r    = lane & 15;
    const int g    = lane >> 4;
    const int colbase = wv * 64 + r;
    const float NEG = -1e9f;
    const i32x4 mq = *(const i32x4*)(mask + 4 * lane);

    float* outb = out + (size_t)s0 * ACOL;
    int buf = 0;

    for (int e2 = 0; e2 < NEXP; ++e2) {
        const int ntiles = ntl[e2];
        if (ntiles == 0) continue;

        // coalesced fragment loads from wpack (1KB per dwordx4 per wave)
        short8   bf1[4];
        unsigned w2[4];
        float    bias[4];
        const uint4* wp = wpack + ((size_t)(e2 * 4 + wv) * 4) * 64 + lane;
        #pragma unroll
        for (int j = 0; j < 4; ++j) {
            bf1[j]  = __builtin_bit_cast(short8, wp[j * 64]);
            w2[j]   = (g == 0) ? w2p[e2 * ACOL + colbase + j * 16] : 0u;
            bias[j] = bout[e2 * ACOL + colbase + j * 16];
        }

        const int tb = goff[e2];
        for (int st = 0; st < ntiles; ++st) {
            const int rb  = tb + (st << 4);
            const int row = rb + r;
            const unsigned sw = (((unsigned)row >> 2) & 3u) << 4;
            const char* rp = (const char*)xs + row * 64;
            short8 a1 = *(const short8*)(rp + (((unsigned)(g * 16)) ^ sw));
            short8 a2 = __builtin_bit_cast(short8,
                          make_uint4(g == 0 ? xt[row] : 0u, 0u, 0u, 0u));

            #pragma unroll
            for (int j = 0; j < 4; ++j) {
                f32x4 a = {bias[j], bias[j], bias[j], bias[j]};
                a = __builtin_amdgcn_mfma_f32_16x16x32_bf16(a1, bf1[j], a, 0, 0, 0);
                short8 b2 = __builtin_bit_cast(short8,
                              make_uint4(w2[j], 0u, 0u, 0u));
                a = __builtin_amdgcn_mfma_f32_16x16x32_bf16(a2, b2, a, 0, 0, 0);
                const int c = colbase + 16 * j;
                #pragma unroll
                for (int i = 0; i < 4; ++i)
                    stg[buf][(g * 4 + i) * STG_STRIDE + c] = a[i];
            }

            BAR_LGKM();   // single barrier: stg[buf] writes visible; prior reads of
                          // stg[buf^1] already landed in regs (lgkmcnt(0) upstream)

            // wave stores 4 full 1KB rows, plain dwordx4 (L2-completing)
            f32x4 v[4];
            unsigned rid[4];
            #pragma unroll
            for (int q = 0; q < 4; ++q) {
                const int lrow = wv * 4 + q;
                rid[q] = rowid[rb + lrow];
                v[q]   = *(const f32x4*)&stg[buf][lrow * STG_STRIDE + 4 * lane];
            }
            #pragma unroll
            for (int q = 0; q < 4; ++q) {
                f32x4 w = v[q];
                w[0] = mq[0] ? w[0] : NEG;
                w[1] = mq[1] ? w[1] : NEG;
                w[2] = mq[2] ? w[2] : NEG;
                w[3] = mq[3] ? w[3] : NEG;
                if (rid[q] != 0xFFFFu)
                    *(f32x4*)(outb + (size_t)rid[q] * ACOL + 4 * lane) = w;
            }
            buf ^= 1;
        }
    }
}

extern "C" void kernel_launch(void* const* d_in, const int* in_sizes, int n_in,
                              void* d_out, int out_size, void* d_ws, size_t ws_size,
                              hipStream_t stream) {
    const float* states    = (const float*)d_in[0];
    const int*   epoch_idx = (const int*)  d_in[1];
    const float* W1        = (const float*)d_in[2];
    const float* b1        = (const float*)d_in[3];
    const float* Wout      = (const float*)d_in[4];
    const float* bout      = (const float*)d_in[5];
    const int*   mask      = (const int*)  d_in[6];
    float*       out       = (float*)d_out;

    const int nB   = in_sizes[0] / SDIM;
    const int grid = (nB + SPB - 1) / SPB;

    uint4*        wpack = (uint4*)d_ws;                       // 196608 B
    unsigned int* w2p   = (unsigned int*)((char*)d_ws + 196608); // 12288 B

    k0_wpack<<<48, 256, 0, stream>>>(Wout, wpack, w2p);
    actor_kernel<<<grid, 256, 0, stream>>>(states, epoch_idx, W1, b1,
                                           wpack, w2p, bout, mask, out, nB);
}